// Round 6
// baseline (62.619 us; speedup 1.0000x reference)
//
#include <hip/hip_runtime.h>
#include <hip/hip_bf16.h>

typedef float f32x4 __attribute__((ext_vector_type(4)));
typedef __bf16 bf16x8 __attribute__((ext_vector_type(8)));
typedef __bf16 bf16x4 __attribute__((ext_vector_type(4)));

#define DEMB 128
#define HIDDEN 64
#define W1T_STRIDE 264   // fallback kernel only

typedef const __attribute__((address_space(1))) void* gas_ptr;
typedef __attribute__((address_space(3))) void* las_ptr;

// ---------------- Phase 0: one-shot W1 -> fragment-ordered bf16 in ws ---------
// wsfrag[tb][cid][j], cid = t*256 + kk*64 + gk*16 + el, j=0..7:
//   wsfrag[(tb*1024+cid)*8 + j] = W1[(tb*128 + kk*32 + gk*8 + j)*64 + 4*el + t]
__global__ __launch_bounds__(256) void w1frag_kernel(
    const float* __restrict__ W1, __bf16* __restrict__ wsfrag)
{
    const int gid = blockIdx.x * 256 + threadIdx.x;   // 0..2047
    if (gid >= 2048) return;
    const int tb  = gid >> 10;
    const int cid = gid & 1023;
    const int el = cid & 15;
    const int gk = (cid >> 4) & 3;
    const int kk = (cid >> 6) & 3;
    const int t  = (cid >> 8) & 3;
    const int kbase = tb * 128 + kk * 32 + gk * 8;
    bf16x8 ch;
#pragma unroll
    for (int j = 0; j < 8; ++j)
        ch[j] = (__bf16)W1[(kbase + j) * HIDDEN + 4 * el + t];
    *reinterpret_cast<bf16x8*>(wsfrag + (size_t)gid * 8) = ch;
}

// ---------------- Phase 1: reg-double-buffered streaming GEMM ----------------
// Per wave: 16-node tile (8 KB contiguous). Prefetch tile t+1 into second
// register set while computing tile t (loads in flight across compute+store).
// W1 frags DMA'd linearly from ws (L2-hot). Output bounced through LDS for
// full-line 16B/lane writes.
__global__ __launch_bounds__(256, 5) void node_part5_kernel(
    const float* __restrict__ src_embs,
    const float* __restrict__ dst_embs,
    const __bf16* __restrict__ wsfrag,
    __bf16* __restrict__ spart,
    __bf16* __restrict__ dpart,
    int n_tiles, int blocks_per_table)
{
    __shared__ __bf16 frag_lds[1024 * 8];   // 16 KB, fragment order
    __shared__ float  bounce[4][512];       // 8 KB

    const int table = (blockIdx.x >= blocks_per_table) ? 1 : 0;
    const int bid = blockIdx.x - table * blocks_per_table;
    const float* __restrict__ E = table ? dst_embs : src_embs;
    __bf16* __restrict__ P = table ? dpart : spart;

    const int lane = threadIdx.x & 63;
    const int el = lane & 15;
    const int gk = lane >> 4;
    const int wid = threadIdx.x >> 6;

    // Linear DMA copy of this table's 16-KB fragment block: 4 chunks of 1 KB/wave.
    {
        const char* src = (const char*)(wsfrag + (size_t)table * 1024 * 8);
#pragma unroll
        for (int r = 0; r < 4; ++r) {
            const int off = (wid * 4 + r) * 1024;
            __builtin_amdgcn_global_load_lds(
                (gas_ptr)(src + off + lane * 16),
                (las_ptr)((char*)frag_lds + off), 16, 0, 0);
        }
        asm volatile("s_waitcnt vmcnt(0)" ::: "memory");
    }
    __syncthreads();

    char* obc = (char*)&bounce[wid][0];
    const int tstride = blocks_per_table * 4;
    int tile = bid * 4 + wid;
    if (tile >= n_tiles) return;

    f32x4 Ra[8], Rb[8];

#define LOADT(T, R)                                                          \
    do {                                                                     \
        const float* rp_ = E + (size_t)(T) * 2048 + el * 128 + gk * 8;       \
        _Pragma("unroll")                                                    \
        for (int kk = 0; kk < 4; ++kk) {                                     \
            (R)[2 * kk]     = *reinterpret_cast<const f32x4*>(rp_ + kk * 32);\
            (R)[2 * kk + 1] = *reinterpret_cast<const f32x4*>(rp_ + kk * 32 + 4);\
        }                                                                    \
    } while (0)

#define COMPUTE_STORE(T, R)                                                  \
    do {                                                                     \
        f32x4 acc[4] = {{0.f,0.f,0.f,0.f},{0.f,0.f,0.f,0.f},                 \
                        {0.f,0.f,0.f,0.f},{0.f,0.f,0.f,0.f}};                \
        _Pragma("unroll")                                                    \
        for (int kk = 0; kk < 4; ++kk) {                                     \
            bf16x8 a;                                                        \
            _Pragma("unroll")                                                \
            for (int j = 0; j < 4; ++j) {                                    \
                a[j]     = (__bf16)(R)[2 * kk][j];                           \
                a[4 + j] = (__bf16)(R)[2 * kk + 1][j];                       \
            }                                                                \
            _Pragma("unroll")                                                \
            for (int t = 0; t < 4; ++t) {                                    \
                const bf16x8 b = *reinterpret_cast<const bf16x8*>(           \
                    &frag_lds[(size_t)((t * 4 + kk) * 4 + gk) * 128 + el * 8]);\
                acc[t] = __builtin_amdgcn_mfma_f32_16x16x32_bf16(a, b, acc[t], 0, 0, 0);\
            }                                                                \
        }                                                                    \
        _Pragma("unroll")                                                    \
        for (int r = 0; r < 4; ++r) {                                        \
            bf16x4 pk;                                                       \
            _Pragma("unroll")                                                \
            for (int t = 0; t < 4; ++t) pk[t] = (__bf16)acc[t][r];           \
            *reinterpret_cast<bf16x4*>(obc + (gk * 4 + r) * 128 + el * 8) = pk;\
        }                                                                    \
        asm volatile("s_waitcnt lgkmcnt(0)" ::: "memory");                   \
        f32x4 c0 = *reinterpret_cast<const f32x4*>(obc + lane * 16);         \
        f32x4 c1 = *reinterpret_cast<const f32x4*>(obc + 1024 + lane * 16);  \
        char* pb = (char*)P + (size_t)(T) * 2048;                            \
        *reinterpret_cast<f32x4*>(pb + lane * 16) = c0;                      \
        *reinterpret_cast<f32x4*>(pb + 1024 + lane * 16) = c1;               \
    } while (0)

    LOADT(tile, Ra);
    bool useA = true;
    while (tile < n_tiles) {
        const int nxt = tile + tstride;
        if (useA) {
            if (nxt < n_tiles) LOADT(nxt, Rb);
            COMPUTE_STORE(tile, Ra);
        } else {
            if (nxt < n_tiles) LOADT(nxt, Ra);
            COMPUTE_STORE(tile, Rb);
        }
        useA = !useA;
        tile = nxt;
    }
#undef LOADT
#undef COMPUTE_STORE
}

// ---------------- Phase 2: per-edge gather of bf16 partials + MLP tail --------
__global__ __launch_bounds__(256, 8) void edge_tail2_kernel(
    const __bf16* __restrict__ spart,
    const __bf16* __restrict__ dpart,
    const int* __restrict__ src_ids,
    const int* __restrict__ dst_ids,
    const float* __restrict__ b1,
    const float* __restrict__ W2,
    const float* __restrict__ b2,
    float* __restrict__ out,
    int n_edges)
{
    const int lane = threadIdx.x & 63;
    const int c = lane & 7;
    float b1v[8], w2v[8];
#pragma unroll
    for (int j = 0; j < 8; ++j) { b1v[j] = b1[c * 8 + j]; w2v[j] = W2[c * 8 + j]; }
    const float bias2 = b2[0];

    int gid = (blockIdx.x * blockDim.x + threadIdx.x) >> 3;
    const int gstride = (gridDim.x * blockDim.x) >> 3;

    for (int e = gid; e < n_edges; e += gstride) {
        const long long sid = src_ids[e];
        const long long did = dst_ids[e];
        const bf16x8 s8 = *reinterpret_cast<const bf16x8*>(spart + sid * HIDDEN + c * 8);
        const bf16x8 d8 = *reinterpret_cast<const bf16x8*>(dpart + did * HIDDEN + c * 8);
        float v = 0.f;
#pragma unroll
        for (int j = 0; j < 8; ++j) {
            float h = (float)s8[j] + (float)d8[j] + b1v[j];
            h = fmaxf(h, 0.f);
            v = fmaf(h, w2v[j], v);
        }
        v += __shfl_xor(v, 1, 64);
        v += __shfl_xor(v, 2, 64);
        v += __shfl_xor(v, 4, 64);
        if (c == 0) out[e] = v + bias2;
    }
}

// ---------------- Fallback (round-1 proven kernel) if ws too small ------------
__global__ __launch_bounds__(256) void edge_mlp_kernel(
    const float* __restrict__ src_embs,
    const float* __restrict__ dst_embs,
    const int* __restrict__ src_ids,
    const int* __restrict__ dst_ids,
    const float* __restrict__ W1,
    const float* __restrict__ b1,
    const float* __restrict__ W2,
    const float* __restrict__ b2,
    float* __restrict__ out,
    int n_edges, int n_groups)
{
    __shared__ __bf16 w1t[64 * W1T_STRIDE];
    for (int s = threadIdx.x; s < 256 * 64; s += 256) {
        int k = s >> 6;
        int n = s & 63;
        w1t[n * W1T_STRIDE + k] = (__bf16)W1[s];
    }
    __syncthreads();

    const int lane = threadIdx.x & 63;
    const int el = lane & 15;
    const int gk = lane >> 4;

    float b1v[4], w2v[4];
#pragma unroll
    for (int t = 0; t < 4; ++t) { b1v[t] = b1[16 * t + el]; w2v[t] = W2[16 * t + el]; }
    const float bias2 = b2[0];

    const int gw0 = blockIdx.x * 4 + (threadIdx.x >> 6);
    const int gstride = gridDim.x * 4;

    for (int g = gw0; g < n_groups; g += gstride) {
        const int e_base = g * 16;
        int e = e_base + el;
        if (e >= n_edges) e = n_edges - 1;
        const long long sid = src_ids[e];
        const long long did = dst_ids[e];
        const float* sp = src_embs + sid * DEMB + gk * 8;
        const float* dp = dst_embs + did * DEMB + gk * 8;

        f32x4 acc[4] = {{0.f,0.f,0.f,0.f},{0.f,0.f,0.f,0.f},
                        {0.f,0.f,0.f,0.f},{0.f,0.f,0.f,0.f}};
#pragma unroll
        for (int kk = 0; kk < 8; ++kk) {
            const float* ap = (kk < 4) ? (sp + kk * 32) : (dp + (kk - 4) * 32);
            f32x4 f0 = *reinterpret_cast<const f32x4*>(ap);
            f32x4 f1 = *reinterpret_cast<const f32x4*>(ap + 4);
            bf16x8 a;
#pragma unroll
            for (int j = 0; j < 4; ++j) { a[j] = (__bf16)f0[j]; a[4+j] = (__bf16)f1[j]; }
#pragma unroll
            for (int t = 0; t < 4; ++t) {
                const bf16x8 bfrag = *reinterpret_cast<const bf16x8*>(
                    &w1t[(16 * t + el) * W1T_STRIDE + kk * 32 + gk * 8]);
                acc[t] = __builtin_amdgcn_mfma_f32_16x16x32_bf16(a, bfrag, acc[t], 0, 0, 0);
            }
        }
        float s0[4];
#pragma unroll
        for (int r = 0; r < 4; ++r) {
            float v = 0.f;
#pragma unroll
            for (int t = 0; t < 4; ++t) {
                float h = acc[t][r] + b1v[t];
                h = fmaxf(h, 0.f);
                v = fmaf(h, w2v[t], v);
            }
#pragma unroll
            for (int m = 1; m < 16; m <<= 1) v += __shfl_xor(v, m, 64);
            s0[r] = v + bias2;
        }
        const int row0 = e_base + gk * 4;
        if (el == 0) {
            if (row0 + 4 <= n_edges) {
                f32x4 o = {s0[0], s0[1], s0[2], s0[3]};
                *reinterpret_cast<f32x4*>(out + row0) = o;
            } else {
#pragma unroll
                for (int r = 0; r < 4; ++r)
                    if (row0 + r < n_edges) out[row0 + r] = s0[r];
            }
        }
    }
}

extern "C" void kernel_launch(void* const* d_in, const int* in_sizes, int n_in,
                              void* d_out, int out_size, void* d_ws, size_t ws_size,
                              hipStream_t stream) {
    const float* src_embs = (const float*)d_in[0];
    const float* dst_embs = (const float*)d_in[1];
    const int*   src_ids  = (const int*)d_in[2];
    const int*   dst_ids  = (const int*)d_in[3];
    const float* W1 = (const float*)d_in[4];
    const float* b1 = (const float*)d_in[5];
    const float* W2 = (const float*)d_in[6];
    const float* b2 = (const float*)d_in[7];
    float* out = (float*)d_out;

    const int n_edges = in_sizes[2];
    const int n_nodes = in_sizes[0] / DEMB;                   // 100000
    const size_t part_elems = (size_t)n_nodes * HIDDEN;
    const size_t need = 2 * part_elems * sizeof(__bf16) + 32768;  // partials + wfrag

    if (ws_size >= need && (n_nodes % 16) == 0) {
        __bf16* spart = (__bf16*)d_ws;
        __bf16* dpart = spart + part_elems;
        __bf16* wsfrag = dpart + part_elems;                  // 32 KB frag table
        const int n_tiles = n_nodes / 16;                     // 6250

        w1frag_kernel<<<8, 256, 0, stream>>>(W1, wsfrag);

        // 6 blocks/CU by LDS (24.6 KB); 768 blocks/table = 1536 total resident.
        int bpt = 768;
        if (bpt * 4 > n_tiles) bpt = (n_tiles + 3) / 4;
        node_part5_kernel<<<2 * bpt, 256, 0, stream>>>(
            src_embs, dst_embs, wsfrag, spart, dpart, n_tiles, bpt);

        int blocks2 = (n_edges + 31) / 32;
        if (blocks2 > 2048) blocks2 = 2048;
        edge_tail2_kernel<<<blocks2, 256, 0, stream>>>(
            spart, dpart, src_ids, dst_ids, b1, W2, b2, out, n_edges);
    } else {
        const int n_groups = (n_edges + 15) / 16;
        int blocks = (n_groups + 3) / 4;
        if (blocks > 1024) blocks = 1024;
        edge_mlp_kernel<<<blocks, 256, 0, stream>>>(
            src_embs, dst_embs, src_ids, dst_ids, W1, b1, W2, b2, out,
            n_edges, n_groups);
    }
}

// Round 7
// 47.298 us; speedup vs baseline: 1.3239x; 1.3239x over previous
//
#include <hip/hip_runtime.h>
#include <hip/hip_bf16.h>

typedef float f32x4 __attribute__((ext_vector_type(4)));
typedef __bf16 bf16x8 __attribute__((ext_vector_type(8)));
typedef __bf16 bf16x4 __attribute__((ext_vector_type(4)));

#define DEMB 128
#define HIDDEN 64
#define W1T_STRIDE 264   // fallback kernel only

typedef const __attribute__((address_space(1))) void* gas_ptr;
typedef __attribute__((address_space(3))) void* las_ptr;

// ---------------- Phase 0: one-shot W1 -> fragment-ordered bf16 in ws ---------
// wsfrag[tb][cid][j], cid = t*256 + kk*64 + gk*16 + el:
//   wsfrag[(tb*1024+cid)*8 + j] = W1[(tb*128 + kk*32 + gk*8 + j)*64 + 4*el + t]
__global__ __launch_bounds__(256) void w1frag_kernel(
    const float* __restrict__ W1, __bf16* __restrict__ wsfrag)
{
    const int gid = blockIdx.x * 256 + threadIdx.x;   // 0..2047
    if (gid >= 2048) return;
    const int tb  = gid >> 10;
    const int cid = gid & 1023;
    const int el = cid & 15;
    const int gk = (cid >> 4) & 3;
    const int kk = (cid >> 6) & 3;
    const int t  = (cid >> 8) & 3;
    const int kbase = tb * 128 + kk * 32 + gk * 8;
    bf16x8 ch;
#pragma unroll
    for (int j = 0; j < 8; ++j)
        ch[j] = (__bf16)W1[(kbase + j) * HIDDEN + 4 * el + t];
    *reinterpret_cast<bf16x8*>(wsfrag + (size_t)gid * 8) = ch;
}

// ---------------- Phase 1: fused both-table streaming GEMM -------------------
// Global tile index tt in [0, 2*n_tiles): table = tt >= n_tiles.
// Each wave owns a CONTIGUOUS chunk of 4 tiles (32 KB span, DRAM page locality)
// and runs a register double-buffer pipeline: loads for tile i+1 issued before
// tile i's compute; compiler inserts counted vmcnt (keeps 8 loads in flight).
// W1 fragments (both halves, 32 KB) DMA'd linearly from ws. Output bounced
// through LDS for full-line 32 B/lane writes (R4-proven: no amplification).
__global__ void node_part6_kernel(
    const float* __restrict__ src_embs,
    const float* __restrict__ dst_embs,
    const __bf16* __restrict__ wsfrag,
    __bf16* __restrict__ spart,
    __bf16* __restrict__ dpart,
    int n_tiles)
{
    __shared__ __bf16 frag_lds[2048 * 8];   // 32 KB: both halves, fragment order
    __shared__ float  bounce[4][512];       // 8 KB

    const int lane = threadIdx.x & 63;
    const int el = lane & 15;
    const int gk = lane >> 4;
    const int wid = threadIdx.x >> 6;

    // Linear DMA copy of the 32-KB fragment table: 8 chunks of 1 KB per wave.
    {
        const char* src = (const char*)wsfrag;
#pragma unroll
        for (int r = 0; r < 8; ++r) {
            const int off = (wid * 8 + r) * 1024;
            __builtin_amdgcn_global_load_lds(
                (gas_ptr)(src + off + lane * 16),
                (las_ptr)((char*)frag_lds + off), 16, 0, 0);
        }
    }
    __syncthreads();   // drains vmcnt/lgkmcnt per compiler barrier semantics

    const int total = 2 * n_tiles;
    const int wave_gid = blockIdx.x * 4 + wid;
    const int base = wave_gid * 4;          // contiguous 4-tile chunk
    if (base >= total) return;
    char* obc = (char*)&bounce[wid][0];

    f32x4 Ra[8], Rb[8];

#define LOADT(TT, R)                                                         \
    do {                                                                     \
        const int tt_ = (TT);                                                \
        const int tb_ = (tt_ >= n_tiles);                                    \
        const float* E_ = tb_ ? dst_embs : src_embs;                         \
        const float* rp_ = E_ + (size_t)(tt_ - tb_ * n_tiles) * 2048         \
                              + el * 128 + gk * 8;                           \
        _Pragma("unroll")                                                    \
        for (int kk = 0; kk < 4; ++kk) {                                     \
            (R)[2 * kk]     = *reinterpret_cast<const f32x4*>(rp_ + kk * 32);\
            (R)[2 * kk + 1] = *reinterpret_cast<const f32x4*>(rp_ + kk * 32 + 4);\
        }                                                                    \
    } while (0)

#define COMPUTE_STORE(TT, R)                                                 \
    do {                                                                     \
        const int tt_ = (TT);                                                \
        const int tb_ = (tt_ >= n_tiles);                                    \
        __bf16* P_ = tb_ ? dpart : spart;                                    \
        const __bf16* fb_ = frag_lds + tb_ * 8192;                           \
        f32x4 acc[4] = {{0.f,0.f,0.f,0.f},{0.f,0.f,0.f,0.f},                 \
                        {0.f,0.f,0.f,0.f},{0.f,0.f,0.f,0.f}};                \
        _Pragma("unroll")                                                    \
        for (int kk = 0; kk < 4; ++kk) {                                     \
            bf16x8 a;                                                        \
            _Pragma("unroll")                                                \
            for (int j = 0; j < 4; ++j) {                                    \
                a[j]     = (__bf16)(R)[2 * kk][j];                           \
                a[4 + j] = (__bf16)(R)[2 * kk + 1][j];                       \
            }                                                                \
            _Pragma("unroll")                                                \
            for (int t = 0; t < 4; ++t) {                                    \
                const bf16x8 b = *reinterpret_cast<const bf16x8*>(           \
                    fb_ + (size_t)((t * 4 + kk) * 4 + gk) * 128 + el * 8);   \
                acc[t] = __builtin_amdgcn_mfma_f32_16x16x32_bf16(a, b, acc[t], 0, 0, 0);\
            }                                                                \
        }                                                                    \
        _Pragma("unroll")                                                    \
        for (int r = 0; r < 4; ++r) {                                        \
            bf16x4 pk;                                                       \
            _Pragma("unroll")                                                \
            for (int t = 0; t < 4; ++t) pk[t] = (__bf16)acc[t][r];           \
            *reinterpret_cast<bf16x4*>(obc + (gk * 4 + r) * 128 + el * 8) = pk;\
        }                                                                    \
        asm volatile("s_waitcnt lgkmcnt(0)" ::: "memory");                   \
        f32x4 c0 = *reinterpret_cast<const f32x4*>(obc + lane * 32);         \
        f32x4 c1 = *reinterpret_cast<const f32x4*>(obc + lane * 32 + 16);    \
        char* pb = (char*)P_ + (size_t)(tt_ - tb_ * n_tiles) * 2048;         \
        *reinterpret_cast<f32x4*>(pb + lane * 32) = c0;                      \
        *reinterpret_cast<f32x4*>(pb + lane * 32 + 16) = c1;                 \
    } while (0)

    const int nrem = total - base;          // 1..4 tiles in this chunk
    if (nrem >= 4) {
        LOADT(base + 0, Ra);
        LOADT(base + 1, Rb);
        COMPUTE_STORE(base + 0, Ra);
        LOADT(base + 2, Ra);
        COMPUTE_STORE(base + 1, Rb);
        LOADT(base + 3, Rb);
        COMPUTE_STORE(base + 2, Ra);
        COMPUTE_STORE(base + 3, Rb);
    } else {
        // tail chunk (only the last active wave): simple serial
        for (int i = 0; i < nrem; ++i) {
            LOADT(base + i, Ra);
            COMPUTE_STORE(base + i, Ra);
        }
    }
#undef LOADT
#undef COMPUTE_STORE
}

// ---------------- Phase 2: per-edge gather of bf16 partials + MLP tail --------
__global__ __launch_bounds__(256, 8) void edge_tail2_kernel(
    const __bf16* __restrict__ spart,
    const __bf16* __restrict__ dpart,
    const int* __restrict__ src_ids,
    const int* __restrict__ dst_ids,
    const float* __restrict__ b1,
    const float* __restrict__ W2,
    const float* __restrict__ b2,
    float* __restrict__ out,
    int n_edges)
{
    const int lane = threadIdx.x & 63;
    const int c = lane & 7;
    float b1v[8], w2v[8];
#pragma unroll
    for (int j = 0; j < 8; ++j) { b1v[j] = b1[c * 8 + j]; w2v[j] = W2[c * 8 + j]; }
    const float bias2 = b2[0];

    int gid = (blockIdx.x * blockDim.x + threadIdx.x) >> 3;
    const int gstride = (gridDim.x * blockDim.x) >> 3;

    for (int e = gid; e < n_edges; e += gstride) {
        const long long sid = src_ids[e];
        const long long did = dst_ids[e];
        const bf16x8 s8 = *reinterpret_cast<const bf16x8*>(spart + sid * HIDDEN + c * 8);
        const bf16x8 d8 = *reinterpret_cast<const bf16x8*>(dpart + did * HIDDEN + c * 8);
        float v = 0.f;
#pragma unroll
        for (int j = 0; j < 8; ++j) {
            float h = (float)s8[j] + (float)d8[j] + b1v[j];
            h = fmaxf(h, 0.f);
            v = fmaf(h, w2v[j], v);
        }
        v += __shfl_xor(v, 1, 64);
        v += __shfl_xor(v, 2, 64);
        v += __shfl_xor(v, 4, 64);
        if (c == 0) out[e] = v + bias2;
    }
}

// ---------------- Fallback (round-1 proven kernel) if ws too small ------------
__global__ __launch_bounds__(256) void edge_mlp_kernel(
    const float* __restrict__ src_embs,
    const float* __restrict__ dst_embs,
    const int* __restrict__ src_ids,
    const int* __restrict__ dst_ids,
    const float* __restrict__ W1,
    const float* __restrict__ b1,
    const float* __restrict__ W2,
    const float* __restrict__ b2,
    float* __restrict__ out,
    int n_edges, int n_groups)
{
    __shared__ __bf16 w1t[64 * W1T_STRIDE];
    for (int s = threadIdx.x; s < 256 * 64; s += 256) {
        int k = s >> 6;
        int n = s & 63;
        w1t[n * W1T_STRIDE + k] = (__bf16)W1[s];
    }
    __syncthreads();

    const int lane = threadIdx.x & 63;
    const int el = lane & 15;
    const int gk = lane >> 4;

    float b1v[4], w2v[4];
#pragma unroll
    for (int t = 0; t < 4; ++t) { b1v[t] = b1[16 * t + el]; w2v[t] = W2[16 * t + el]; }
    const float bias2 = b2[0];

    const int gw0 = blockIdx.x * 4 + (threadIdx.x >> 6);
    const int gstride = gridDim.x * 4;

    for (int g = gw0; g < n_groups; g += gstride) {
        const int e_base = g * 16;
        int e = e_base + el;
        if (e >= n_edges) e = n_edges - 1;
        const long long sid = src_ids[e];
        const long long did = dst_ids[e];
        const float* sp = src_embs + sid * DEMB + gk * 8;
        const float* dp = dst_embs + did * DEMB + gk * 8;

        f32x4 acc[4] = {{0.f,0.f,0.f,0.f},{0.f,0.f,0.f,0.f},
                        {0.f,0.f,0.f,0.f},{0.f,0.f,0.f,0.f}};
#pragma unroll
        for (int kk = 0; kk < 8; ++kk) {
            const float* ap = (kk < 4) ? (sp + kk * 32) : (dp + (kk - 4) * 32);
            f32x4 f0 = *reinterpret_cast<const f32x4*>(ap);
            f32x4 f1 = *reinterpret_cast<const f32x4*>(ap + 4);
            bf16x8 a;
#pragma unroll
            for (int j = 0; j < 4; ++j) { a[j] = (__bf16)f0[j]; a[4+j] = (__bf16)f1[j]; }
#pragma unroll
            for (int t = 0; t < 4; ++t) {
                const bf16x8 bfrag = *reinterpret_cast<const bf16x8*>(
                    &w1t[(16 * t + el) * W1T_STRIDE + kk * 32 + gk * 8]);
                acc[t] = __builtin_amdgcn_mfma_f32_16x16x32_bf16(a, bfrag, acc[t], 0, 0, 0);
            }
        }
        float s0[4];
#pragma unroll
        for (int r = 0; r < 4; ++r) {
            float v = 0.f;
#pragma unroll
            for (int t = 0; t < 4; ++t) {
                float h = acc[t][r] + b1v[t];
                h = fmaxf(h, 0.f);
                v = fmaf(h, w2v[t], v);
            }
#pragma unroll
            for (int m = 1; m < 16; m <<= 1) v += __shfl_xor(v, m, 64);
            s0[r] = v + bias2;
        }
        const int row0 = e_base + gk * 4;
        if (el == 0) {
            if (row0 + 4 <= n_edges) {
                f32x4 o = {s0[0], s0[1], s0[2], s0[3]};
                *reinterpret_cast<f32x4*>(out + row0) = o;
            } else {
#pragma unroll
                for (int r = 0; r < 4; ++r)
                    if (row0 + r < n_edges) out[row0 + r] = s0[r];
            }
        }
    }
}

extern "C" void kernel_launch(void* const* d_in, const int* in_sizes, int n_in,
                              void* d_out, int out_size, void* d_ws, size_t ws_size,
                              hipStream_t stream) {
    const float* src_embs = (const float*)d_in[0];
    const float* dst_embs = (const float*)d_in[1];
    const int*   src_ids  = (const int*)d_in[2];
    const int*   dst_ids  = (const int*)d_in[3];
    const float* W1 = (const float*)d_in[4];
    const float* b1 = (const float*)d_in[5];
    const float* W2 = (const float*)d_in[6];
    const float* b2 = (const float*)d_in[7];
    float* out = (float*)d_out;

    const int n_edges = in_sizes[2];
    const int n_nodes = in_sizes[0] / DEMB;                   // 100000
    const size_t part_elems = (size_t)n_nodes * HIDDEN;
    const size_t need = 2 * part_elems * sizeof(__bf16) + 32768;

    if (ws_size >= need && (n_nodes % 16) == 0) {
        __bf16* spart = (__bf16*)d_ws;
        __bf16* dpart = spart + part_elems;
        __bf16* wsfrag = dpart + part_elems;                  // 32 KB frag table
        const int n_tiles = n_nodes / 16;                     // 6250

        w1frag_kernel<<<8, 256, 0, stream>>>(W1, wsfrag);

        // 16 tiles per block (4 waves x 4-tile contiguous chunks)
        const int total = 2 * n_tiles;                        // 12500
        int blocks1 = (total + 15) / 16;                      // 782
        node_part6_kernel<<<blocks1, 256, 0, stream>>>(
            src_embs, dst_embs, wsfrag, spart, dpart, n_tiles);

        int blocks2 = (n_edges + 31) / 32;
        if (blocks2 > 2048) blocks2 = 2048;
        edge_tail2_kernel<<<blocks2, 256, 0, stream>>>(
            spart, dpart, src_ids, dst_ids, b1, W2, b2, out, n_edges);
    } else {
        const int n_groups = (n_edges + 15) / 16;
        int blocks = (n_groups + 3) / 4;
        if (blocks > 1024) blocks = 1024;
        edge_mlp_kernel<<<blocks, 256, 0, stream>>>(
            src_embs, dst_embs, src_ids, dst_ids, W1, b1, W2, b2, out,
            n_edges, n_groups);
    }
}

// Round 9
// 44.682 us; speedup vs baseline: 1.4014x; 1.0586x over previous
//
#include <hip/hip_runtime.h>
#include <hip/hip_bf16.h>

typedef float f32x4 __attribute__((ext_vector_type(4)));
typedef __bf16 bf16x8 __attribute__((ext_vector_type(8)));
typedef __bf16 bf16x4 __attribute__((ext_vector_type(4)));

#define DEMB 128
#define HIDDEN 64
#define W1T_STRIDE 264   // fallback kernel only

typedef const __attribute__((address_space(1))) void* gas_ptr;
typedef __attribute__((address_space(3))) void* las_ptr;

// ---------------- Phase 0: one-shot W1 -> fragment-ordered bf16 in ws ---------
// wsfrag[tb][cid][j], cid = t*256 + kk*64 + gk*16 + el:
//   wsfrag[(tb*1024+cid)*8 + j] = W1[(tb*128 + kk*32 + gk*8 + j)*64 + 4*el + t]
__global__ __launch_bounds__(256) void w1frag_kernel(
    const float* __restrict__ W1, __bf16* __restrict__ wsfrag)
{
    const int gid = blockIdx.x * 256 + threadIdx.x;   // 0..2047
    if (gid >= 2048) return;
    const int tb  = gid >> 10;
    const int cid = gid & 1023;
    const int el = cid & 15;
    const int gk = (cid >> 4) & 3;
    const int kk = (cid >> 6) & 3;
    const int t  = (cid >> 8) & 3;
    const int kbase = tb * 128 + kk * 32 + gk * 8;
    bf16x8 ch;
#pragma unroll
    for (int j = 0; j < 8; ++j)
        ch[j] = (__bf16)W1[(kbase + j) * HIDDEN + 4 * el + t];
    *reinterpret_cast<bf16x8*>(wsfrag + (size_t)gid * 8) = ch;
}

// ---------------- Phase 1: max-occupancy reg-load GEMM + bounce writes --------
// Per wave: 16-node tile (8 KB contiguous). Lane (el,gk) loads 8x f32x4 pairs
// directly to registers (compiler-managed waits, no manual vmcnt). W1 half in
// 16-KB fragment-ordered LDS (linear DMA from ws). Output tile bounced through
// per-wave 2-KB LDS for full-line 32 B/lane global writes.
// LDS = 16 + 8 = 24 KB -> 6 blocks/CU; launch_bounds(256,6) -> 24 waves/CU.
__global__ __launch_bounds__(256, 6) void node_part8_kernel(
    const float* __restrict__ src_embs,
    const float* __restrict__ dst_embs,
    const __bf16* __restrict__ wsfrag,
    __bf16* __restrict__ spart,
    __bf16* __restrict__ dpart,
    int n_tiles, int blocks_per_table)
{
    __shared__ __bf16 frag_lds[1024 * 8];   // 16 KB: this table's half
    __shared__ float  bounce[4][512];       // 8 KB: 4 waves x 2 KB

    const int table = (blockIdx.x >= blocks_per_table) ? 1 : 0;
    const int bid = blockIdx.x - table * blocks_per_table;
    const float* __restrict__ E = table ? dst_embs : src_embs;
    __bf16* __restrict__ P = table ? dpart : spart;

    const int lane = threadIdx.x & 63;
    const int el = lane & 15;
    const int gk = lane >> 4;
    const int wid = threadIdx.x >> 6;

    // Linear DMA copy of this table's 16-KB fragment block: 4 x 1 KB per wave.
    {
        const char* src = (const char*)(wsfrag + (size_t)table * 1024 * 8);
#pragma unroll
        for (int r = 0; r < 4; ++r) {
            const int off = (wid * 4 + r) * 1024;
            __builtin_amdgcn_global_load_lds(
                (gas_ptr)(src + off + lane * 16),
                (las_ptr)((char*)frag_lds + off), 16, 0, 0);
        }
        asm volatile("s_waitcnt vmcnt(0)" ::: "memory");
    }
    __syncthreads();

    char* obc = (char*)&bounce[wid][0];
    const int tstride = blocks_per_table * 4;

    for (int tile = bid * 4 + wid; tile < n_tiles; tile += tstride) {
        const float* rp = E + (size_t)tile * 2048 + el * 128 + gk * 8;

        // 8 x 16-B register loads (32 B contiguous per (el,gk) per kk).
        f32x4 R[8];
#pragma unroll
        for (int kk = 0; kk < 4; ++kk) {
            R[2 * kk]     = *reinterpret_cast<const f32x4*>(rp + kk * 32);
            R[2 * kk + 1] = *reinterpret_cast<const f32x4*>(rp + kk * 32 + 4);
        }

        f32x4 acc[4] = {{0.f,0.f,0.f,0.f},{0.f,0.f,0.f,0.f},
                        {0.f,0.f,0.f,0.f},{0.f,0.f,0.f,0.f}};
#pragma unroll
        for (int kk = 0; kk < 4; ++kk) {
            bf16x8 a;
#pragma unroll
            for (int j = 0; j < 4; ++j) {
                a[j]     = (__bf16)R[2 * kk][j];
                a[4 + j] = (__bf16)R[2 * kk + 1][j];
            }
#pragma unroll
            for (int t = 0; t < 4; ++t) {
                const bf16x8 b = *reinterpret_cast<const bf16x8*>(
                    &frag_lds[(size_t)((t * 4 + kk) * 4 + gk) * 128 + el * 8]);
                acc[t] = __builtin_amdgcn_mfma_f32_16x16x32_bf16(a, b, acc[t], 0, 0, 0);
            }
        }

        // Bounce output tile (16 x 64 bf16 = 2 KB) -> full-line 32 B/lane writes.
#pragma unroll
        for (int r = 0; r < 4; ++r) {
            bf16x4 pk;
#pragma unroll
            for (int t = 0; t < 4; ++t) pk[t] = (__bf16)acc[t][r];
            *reinterpret_cast<bf16x4*>(obc + (gk * 4 + r) * 128 + el * 8) = pk;
        }
        asm volatile("s_waitcnt lgkmcnt(0)" ::: "memory");
        f32x4 c0 = *reinterpret_cast<const f32x4*>(obc + lane * 32);
        f32x4 c1 = *reinterpret_cast<const f32x4*>(obc + lane * 32 + 16);
        char* pb = (char*)P + (size_t)tile * 2048;
        *reinterpret_cast<f32x4*>(pb + lane * 32) = c0;
        *reinterpret_cast<f32x4*>(pb + lane * 32 + 16) = c1;
    }
}

// ---------------- Phase 2: per-edge gather of bf16 partials + MLP tail --------
__global__ __launch_bounds__(256, 8) void edge_tail2_kernel(
    const __bf16* __restrict__ spart,
    const __bf16* __restrict__ dpart,
    const int* __restrict__ src_ids,
    const int* __restrict__ dst_ids,
    const float* __restrict__ b1,
    const float* __restrict__ W2,
    const float* __restrict__ b2,
    float* __restrict__ out,
    int n_edges)
{
    const int lane = threadIdx.x & 63;
    const int c = lane & 7;
    float b1v[8], w2v[8];
#pragma unroll
    for (int j = 0; j < 8; ++j) { b1v[j] = b1[c * 8 + j]; w2v[j] = W2[c * 8 + j]; }
    const float bias2 = b2[0];

    int gid = (blockIdx.x * blockDim.x + threadIdx.x) >> 3;
    const int gstride = (gridDim.x * blockDim.x) >> 3;

    for (int e = gid; e < n_edges; e += gstride) {
        const long long sid = src_ids[e];
        const long long did = dst_ids[e];
        const bf16x8 s8 = *reinterpret_cast<const bf16x8*>(spart + sid * HIDDEN + c * 8);
        const bf16x8 d8 = *reinterpret_cast<const bf16x8*>(dpart + did * HIDDEN + c * 8);
        float v = 0.f;
#pragma unroll
        for (int j = 0; j < 8; ++j) {
            float h = (float)s8[j] + (float)d8[j] + b1v[j];
            h = fmaxf(h, 0.f);
            v = fmaf(h, w2v[j], v);
        }
        v += __shfl_xor(v, 1, 64);
        v += __shfl_xor(v, 2, 64);
        v += __shfl_xor(v, 4, 64);
        if (c == 0) out[e] = v + bias2;
    }
}

// ---------------- Fallback (round-1 proven kernel) if ws too small ------------
__global__ __launch_bounds__(256) void edge_mlp_kernel(
    const float* __restrict__ src_embs,
    const float* __restrict__ dst_embs,
    const int* __restrict__ src_ids,
    const int* __restrict__ dst_ids,
    const float* __restrict__ W1,
    const float* __restrict__ b1,
    const float* __restrict__ W2,
    const float* __restrict__ b2,
    float* __restrict__ out,
    int n_edges, int n_groups)
{
    __shared__ __bf16 w1t[64 * W1T_STRIDE];
    for (int s = threadIdx.x; s < 256 * 64; s += 256) {
        int k = s >> 6;
        int n = s & 63;
        w1t[n * W1T_STRIDE + k] = (__bf16)W1[s];
    }
    __syncthreads();

    const int lane = threadIdx.x & 63;
    const int el = lane & 15;
    const int gk = lane >> 4;

    float b1v[4], w2v[4];
#pragma unroll
    for (int t = 0; t < 4; ++t) { b1v[t] = b1[16 * t + el]; w2v[t] = W2[16 * t + el]; }
    const float bias2 = b2[0];

    const int gw0 = blockIdx.x * 4 + (threadIdx.x >> 6);
    const int gstride = gridDim.x * 4;

    for (int g = gw0; g < n_groups; g += gstride) {
        const int e_base = g * 16;
        int e = e_base + el;
        if (e >= n_edges) e = n_edges - 1;
        const long long sid = src_ids[e];
        const long long did = dst_ids[e];
        const float* sp = src_embs + sid * DEMB + gk * 8;
        const float* dp = dst_embs + did * DEMB + gk * 8;

        f32x4 acc[4] = {{0.f,0.f,0.f,0.f},{0.f,0.f,0.f,0.f},
                        {0.f,0.f,0.f,0.f},{0.f,0.f,0.f,0.f}};
#pragma unroll
        for (int kk = 0; kk < 8; ++kk) {
            const float* ap = (kk < 4) ? (sp + kk * 32) : (dp + (kk - 4) * 32);
            f32x4 f0 = *reinterpret_cast<const f32x4*>(ap);
            f32x4 f1 = *reinterpret_cast<const f32x4*>(ap + 4);
            bf16x8 a;
#pragma unroll
            for (int j = 0; j < 4; ++j) { a[j] = (__bf16)f0[j]; a[4+j] = (__bf16)f1[j]; }
#pragma unroll
            for (int t = 0; t < 4; ++t) {
                const bf16x8 bfrag = *reinterpret_cast<const bf16x8*>(
                    &w1t[(16 * t + el) * W1T_STRIDE + kk * 32 + gk * 8]);
                acc[t] = __builtin_amdgcn_mfma_f32_16x16x32_bf16(a, bfrag, acc[t], 0, 0, 0);
            }
        }
        float s0[4];
#pragma unroll
        for (int r = 0; r < 4; ++r) {
            float v = 0.f;
#pragma unroll
            for (int t = 0; t < 4; ++t) {
                float h = acc[t][r] + b1v[t];
                h = fmaxf(h, 0.f);
                v = fmaf(h, w2v[t], v);
            }
#pragma unroll
            for (int m = 1; m < 16; m <<= 1) v += __shfl_xor(v, m, 64);
            s0[r] = v + bias2;
        }
        const int row0 = e_base + gk * 4;
        if (el == 0) {
            if (row0 + 4 <= n_edges) {
                f32x4 o = {s0[0], s0[1], s0[2], s0[3]};
                *reinterpret_cast<f32x4*>(out + row0) = o;
            } else {
#pragma unroll
                for (int r = 0; r < 4; ++r)
                    if (row0 + r < n_edges) out[row0 + r] = s0[r];
            }
        }
    }
}

extern "C" void kernel_launch(void* const* d_in, const int* in_sizes, int n_in,
                              void* d_out, int out_size, void* d_ws, size_t ws_size,
                              hipStream_t stream) {
    const float* src_embs = (const float*)d_in[0];
    const float* dst_embs = (const float*)d_in[1];
    const int*   src_ids  = (const int*)d_in[2];
    const int*   dst_ids  = (const int*)d_in[3];
    const float* W1 = (const float*)d_in[4];
    const float* b1 = (const float*)d_in[5];
    const float* W2 = (const float*)d_in[6];
    const float* b2 = (const float*)d_in[7];
    float* out = (float*)d_out;

    const int n_edges = in_sizes[2];
    const int n_nodes = in_sizes[0] / DEMB;                   // 100000
    const size_t part_elems = (size_t)n_nodes * HIDDEN;
    const size_t need = 2 * part_elems * sizeof(__bf16) + 32768;

    if (ws_size >= need && (n_nodes % 16) == 0) {
        __bf16* spart = (__bf16*)d_ws;
        __bf16* dpart = spart + part_elems;
        __bf16* wsfrag = dpart + part_elems;                  // 32 KB frag table
        const int n_tiles = n_nodes / 16;                     // 6250

        w1frag_kernel<<<8, 256, 0, stream>>>(W1, wsfrag);

        // 768 blocks/table = 1536 total = 6 blocks/CU (24 KB LDS, 24 waves/CU).
        int bpt = 768;
        if (bpt * 4 > n_tiles) bpt = (n_tiles + 3) / 4;
        node_part8_kernel<<<2 * bpt, 256, 0, stream>>>(
            src_embs, dst_embs, wsfrag, spart, dpart, n_tiles, bpt);

        int blocks2 = (n_edges + 31) / 32;
        if (blocks2 > 2048) blocks2 = 2048;
        edge_tail2_kernel<<<blocks2, 256, 0, stream>>>(
            spart, dpart, src_ids, dst_ids, b1, W2, b2, out, n_edges);
    } else {
        const int n_groups = (n_edges + 15) / 16;
        int blocks = (n_groups + 3) / 4;
        if (blocks > 1024) blocks = 1024;
        edge_mlp_kernel<<<blocks, 256, 0, stream>>>(
            src_embs, dst_embs, src_ids, dst_ids, W1, b1, W2, b2, out,
            n_edges, n_groups);
    }
}

// Round 10
// 43.336 us; speedup vs baseline: 1.4450x; 1.0310x over previous
//
#include <hip/hip_runtime.h>
#include <hip/hip_bf16.h>

typedef float f32x4 __attribute__((ext_vector_type(4)));
typedef __bf16 bf16x8 __attribute__((ext_vector_type(8)));
typedef __bf16 bf16x4 __attribute__((ext_vector_type(4)));

#define DEMB 128
#define HIDDEN 64
#define W1T_STRIDE 264   // fallback kernel only

typedef const __attribute__((address_space(1))) void* gas_ptr;
typedef __attribute__((address_space(3))) void* las_ptr;

// ---------------- Phase 0: one-shot W1 -> fragment-ordered bf16 in ws ---------
__global__ __launch_bounds__(256) void w1frag_kernel(
    const float* __restrict__ W1, __bf16* __restrict__ wsfrag)
{
    const int gid = blockIdx.x * 256 + threadIdx.x;   // 0..2047
    if (gid >= 2048) return;
    const int tb  = gid >> 10;
    const int cid = gid & 1023;
    const int el = cid & 15;
    const int gk = (cid >> 4) & 3;
    const int kk = (cid >> 6) & 3;
    const int t  = (cid >> 8) & 3;
    const int kbase = tb * 128 + kk * 32 + gk * 8;
    bf16x8 ch;
#pragma unroll
    for (int j = 0; j < 8; ++j)
        ch[j] = (__bf16)W1[(kbase + j) * HIDDEN + 4 * el + t];
    *reinterpret_cast<bf16x8*>(wsfrag + (size_t)gid * 8) = ch;
}

// ---------------- Phase 1: sched_barrier-pinned reg double-buffer ------------
// Per wave: 16-node tile (8 KB contiguous). Loads for tile t+1 are issued
// BEFORE tile t's compute and pinned there with sched_barrier(0) so the
// scheduler cannot sink them (R7 failure mode). Compiler-managed waitcnt
// (no hand-counted vmcnt -> no R8-style race). W1 half in 16-KB
// fragment-ordered LDS; output bounced through LDS for full-line writes.
__global__ __launch_bounds__(256) void node_part9_kernel(
    const float* __restrict__ src_embs,
    const float* __restrict__ dst_embs,
    const __bf16* __restrict__ wsfrag,
    __bf16* __restrict__ spart,
    __bf16* __restrict__ dpart,
    int n_tiles, int blocks_per_table)
{
    __shared__ __bf16 frag_lds[1024 * 8];   // 16 KB: this table's half
    __shared__ float  bounce[4][512];       // 8 KB: 4 waves x 2 KB

    const int table = (blockIdx.x >= blocks_per_table) ? 1 : 0;
    const int bid = blockIdx.x - table * blocks_per_table;
    const float* __restrict__ E = table ? dst_embs : src_embs;
    __bf16* __restrict__ P = table ? dpart : spart;

    const int lane = threadIdx.x & 63;
    const int el = lane & 15;
    const int gk = lane >> 4;
    const int wid = threadIdx.x >> 6;

    // Linear DMA copy of this table's 16-KB fragment block: 4 x 1 KB per wave.
    {
        const char* src = (const char*)(wsfrag + (size_t)table * 1024 * 8);
#pragma unroll
        for (int r = 0; r < 4; ++r) {
            const int off = (wid * 4 + r) * 1024;
            __builtin_amdgcn_global_load_lds(
                (gas_ptr)(src + off + lane * 16),
                (las_ptr)((char*)frag_lds + off), 16, 0, 0);
        }
        asm volatile("s_waitcnt vmcnt(0)" ::: "memory");
    }
    __syncthreads();

    char* obc = (char*)&bounce[wid][0];
    const int tstride = blocks_per_table * 4;
    int tile = bid * 4 + wid;
    if (tile >= n_tiles) return;

    f32x4 Ra[8], Rb[8];

#define LOADT(T, R)                                                          \
    do {                                                                     \
        const float* rp_ = E + (size_t)(T) * 2048 + el * 128 + gk * 8;       \
        _Pragma("unroll")                                                    \
        for (int kk = 0; kk < 4; ++kk) {                                     \
            (R)[2 * kk]     = *reinterpret_cast<const f32x4*>(rp_ + kk * 32);\
            (R)[2 * kk + 1] = *reinterpret_cast<const f32x4*>(rp_ + kk * 32 + 4);\
        }                                                                    \
    } while (0)

#define COMPUTE_STORE(T, R)                                                  \
    do {                                                                     \
        f32x4 acc[4] = {{0.f,0.f,0.f,0.f},{0.f,0.f,0.f,0.f},                 \
                        {0.f,0.f,0.f,0.f},{0.f,0.f,0.f,0.f}};                \
        _Pragma("unroll")                                                    \
        for (int kk = 0; kk < 4; ++kk) {                                     \
            bf16x8 a;                                                        \
            _Pragma("unroll")                                                \
            for (int j = 0; j < 4; ++j) {                                    \
                a[j]     = (__bf16)(R)[2 * kk][j];                           \
                a[4 + j] = (__bf16)(R)[2 * kk + 1][j];                       \
            }                                                                \
            _Pragma("unroll")                                                \
            for (int t = 0; t < 4; ++t) {                                    \
                const bf16x8 b = *reinterpret_cast<const bf16x8*>(           \
                    &frag_lds[(size_t)((t * 4 + kk) * 4 + gk) * 128 + el * 8]);\
                acc[t] = __builtin_amdgcn_mfma_f32_16x16x32_bf16(a, b, acc[t], 0, 0, 0);\
            }                                                                \
        }                                                                    \
        _Pragma("unroll")                                                    \
        for (int r = 0; r < 4; ++r) {                                        \
            bf16x4 pk;                                                       \
            _Pragma("unroll")                                                \
            for (int t = 0; t < 4; ++t) pk[t] = (__bf16)acc[t][r];           \
            *reinterpret_cast<bf16x4*>(obc + (gk * 4 + r) * 128 + el * 8) = pk;\
        }                                                                    \
        asm volatile("s_waitcnt lgkmcnt(0)" ::: "memory");                   \
        f32x4 c0 = *reinterpret_cast<const f32x4*>(obc + lane * 32);         \
        f32x4 c1 = *reinterpret_cast<const f32x4*>(obc + lane * 32 + 16);    \
        char* pb = (char*)P + (size_t)(T) * 2048;                            \
        *reinterpret_cast<f32x4*>(pb + lane * 32) = c0;                      \
        *reinterpret_cast<f32x4*>(pb + lane * 32 + 16) = c1;                 \
    } while (0)

    LOADT(tile, Ra);
    bool useA = true;
    while (true) {
        const int nxt = tile + tstride;
        if (useA) {
            if (nxt < n_tiles) LOADT(nxt, Rb);
            __builtin_amdgcn_sched_barrier(0);   // pin prefetch before compute
            COMPUTE_STORE(tile, Ra);
        } else {
            if (nxt < n_tiles) LOADT(nxt, Ra);
            __builtin_amdgcn_sched_barrier(0);
            COMPUTE_STORE(tile, Rb);
        }
        useA = !useA;
        tile = nxt;
        if (tile >= n_tiles) break;
    }
#undef LOADT
#undef COMPUTE_STORE
}

// ---------------- Phase 2: per-edge gather of bf16 partials + MLP tail --------
__global__ __launch_bounds__(256, 8) void edge_tail2_kernel(
    const __bf16* __restrict__ spart,
    const __bf16* __restrict__ dpart,
    const int* __restrict__ src_ids,
    const int* __restrict__ dst_ids,
    const float* __restrict__ b1,
    const float* __restrict__ W2,
    const float* __restrict__ b2,
    float* __restrict__ out,
    int n_edges)
{
    const int lane = threadIdx.x & 63;
    const int c = lane & 7;
    float b1v[8], w2v[8];
#pragma unroll
    for (int j = 0; j < 8; ++j) { b1v[j] = b1[c * 8 + j]; w2v[j] = W2[c * 8 + j]; }
    const float bias2 = b2[0];

    int gid = (blockIdx.x * blockDim.x + threadIdx.x) >> 3;
    const int gstride = (gridDim.x * blockDim.x) >> 3;

    for (int e = gid; e < n_edges; e += gstride) {
        const long long sid = src_ids[e];
        const long long did = dst_ids[e];
        const bf16x8 s8 = *reinterpret_cast<const bf16x8*>(spart + sid * HIDDEN + c * 8);
        const bf16x8 d8 = *reinterpret_cast<const bf16x8*>(dpart + did * HIDDEN + c * 8);
        float v = 0.f;
#pragma unroll
        for (int j = 0; j < 8; ++j) {
            float h = (float)s8[j] + (float)d8[j] + b1v[j];
            h = fmaxf(h, 0.f);
            v = fmaf(h, w2v[j], v);
        }
        v += __shfl_xor(v, 1, 64);
        v += __shfl_xor(v, 2, 64);
        v += __shfl_xor(v, 4, 64);
        if (c == 0) out[e] = v + bias2;
    }
}

// ---------------- Fallback (round-1 proven kernel) if ws too small ------------
__global__ __launch_bounds__(256) void edge_mlp_kernel(
    const float* __restrict__ src_embs,
    const float* __restrict__ dst_embs,
    const int* __restrict__ src_ids,
    const int* __restrict__ dst_ids,
    const float* __restrict__ W1,
    const float* __restrict__ b1,
    const float* __restrict__ W2,
    const float* __restrict__ b2,
    float* __restrict__ out,
    int n_edges, int n_groups)
{
    __shared__ __bf16 w1t[64 * W1T_STRIDE];
    for (int s = threadIdx.x; s < 256 * 64; s += 256) {
        int k = s >> 6;
        int n = s & 63;
        w1t[n * W1T_STRIDE + k] = (__bf16)W1[s];
    }
    __syncthreads();

    const int lane = threadIdx.x & 63;
    const int el = lane & 15;
    const int gk = lane >> 4;

    float b1v[4], w2v[4];
#pragma unroll
    for (int t = 0; t < 4; ++t) { b1v[t] = b1[16 * t + el]; w2v[t] = W2[16 * t + el]; }
    const float bias2 = b2[0];

    const int gw0 = blockIdx.x * 4 + (threadIdx.x >> 6);
    const int gstride = gridDim.x * 4;

    for (int g = gw0; g < n_groups; g += gstride) {
        const int e_base = g * 16;
        int e = e_base + el;
        if (e >= n_edges) e = n_edges - 1;
        const long long sid = src_ids[e];
        const long long did = dst_ids[e];
        const float* sp = src_embs + sid * DEMB + gk * 8;
        const float* dp = dst_embs + did * DEMB + gk * 8;

        f32x4 acc[4] = {{0.f,0.f,0.f,0.f},{0.f,0.f,0.f,0.f},
                        {0.f,0.f,0.f,0.f},{0.f,0.f,0.f,0.f}};
#pragma unroll
        for (int kk = 0; kk < 8; ++kk) {
            const float* ap = (kk < 4) ? (sp + kk * 32) : (dp + (kk - 4) * 32);
            f32x4 f0 = *reinterpret_cast<const f32x4*>(ap);
            f32x4 f1 = *reinterpret_cast<const f32x4*>(ap + 4);
            bf16x8 a;
#pragma unroll
            for (int j = 0; j < 4; ++j) { a[j] = (__bf16)f0[j]; a[4+j] = (__bf16)f1[j]; }
#pragma unroll
            for (int t = 0; t < 4; ++t) {
                const bf16x8 bfrag = *reinterpret_cast<const bf16x8*>(
                    &w1t[(16 * t + el) * W1T_STRIDE + kk * 32 + gk * 8]);
                acc[t] = __builtin_amdgcn_mfma_f32_16x16x32_bf16(a, bfrag, acc[t], 0, 0, 0);
            }
        }
        float s0[4];
#pragma unroll
        for (int r = 0; r < 4; ++r) {
            float v = 0.f;
#pragma unroll
            for (int t = 0; t < 4; ++t) {
                float h = acc[t][r] + b1v[t];
                h = fmaxf(h, 0.f);
                v = fmaf(h, w2v[t], v);
            }
#pragma unroll
            for (int m = 1; m < 16; m <<= 1) v += __shfl_xor(v, m, 64);
            s0[r] = v + bias2;
        }
        const int row0 = e_base + gk * 4;
        if (el == 0) {
            if (row0 + 4 <= n_edges) {
                f32x4 o = {s0[0], s0[1], s0[2], s0[3]};
                *reinterpret_cast<f32x4*>(out + row0) = o;
            } else {
#pragma unroll
                for (int r = 0; r < 4; ++r)
                    if (row0 + r < n_edges) out[row0 + r] = s0[r];
            }
        }
    }
}

extern "C" void kernel_launch(void* const* d_in, const int* in_sizes, int n_in,
                              void* d_out, int out_size, void* d_ws, size_t ws_size,
                              hipStream_t stream) {
    const float* src_embs = (const float*)d_in[0];
    const float* dst_embs = (const float*)d_in[1];
    const int*   src_ids  = (const int*)d_in[2];
    const int*   dst_ids  = (const int*)d_in[3];
    const float* W1 = (const float*)d_in[4];
    const float* b1 = (const float*)d_in[5];
    const float* W2 = (const float*)d_in[6];
    const float* b2 = (const float*)d_in[7];
    float* out = (float*)d_out;

    const int n_edges = in_sizes[2];
    const int n_nodes = in_sizes[0] / DEMB;                   // 100000
    const size_t part_elems = (size_t)n_nodes * HIDDEN;
    const size_t need = 2 * part_elems * sizeof(__bf16) + 32768;

    if (ws_size >= need && (n_nodes % 16) == 0) {
        __bf16* spart = (__bf16*)d_ws;
        __bf16* dpart = spart + part_elems;
        __bf16* wsfrag = dpart + part_elems;                  // 32 KB frag table
        const int n_tiles = n_nodes / 16;                     // 6250

        w1frag_kernel<<<8, 256, 0, stream>>>(W1, wsfrag);

        // 384 blocks/table = 768 total = 3 blocks/CU; ~4 tiles per wave so the
        // double-buffer pipeline has a steady state.
        int bpt = 384;
        if (bpt * 4 > n_tiles) bpt = (n_tiles + 3) / 4;
        node_part9_kernel<<<2 * bpt, 256, 0, stream>>>(
            src_embs, dst_embs, wsfrag, spart, dpart, n_tiles, bpt);

        int blocks2 = (n_edges + 31) / 32;
        if (blocks2 > 2048) blocks2 = 2048;
        edge_tail2_kernel<<<blocks2, 256, 0, stream>>>(
            spart, dpart, src_ids, dst_ids, b1, W2, b2, out, n_edges);
    } else {
        const int n_groups = (n_edges + 15) / 16;
        int blocks = (n_groups + 3) / 4;
        if (blocks > 1024) blocks = 1024;
        edge_mlp_kernel<<<blocks, 256, 0, stream>>>(
            src_embs, dst_embs, src_ids, dst_ids, W1, b1, W2, b2, out,
            n_edges, n_groups);
    }
}